// Round 5
// baseline (129.278 us; speedup 1.0000x reference)
//
#include <hip/hip_runtime.h>
#include <math.h>

#define B_ROWS 4096
#define T_COLS 4096
#define NTHREADS 1024            // one block per row, thread owns one float4
#define NWAVES (NTHREADS / 64)   // 16

// Force a (wave-uniform) float into an SGPR.
__device__ __forceinline__ float rfl(float v) {
    return __int_as_float(__builtin_amdgcn_readfirstlane(__float_as_int(v)));
}

__global__ __launch_bounds__(NTHREADS) void garch_fused(
    const float* __restrict__ x,
    const float* __restrict__ p_omega_log,
    const float* __restrict__ p_alpha_log,
    const float* __restrict__ p_beta_log,
    float* __restrict__ out)
{
    __shared__ float wA[NWAVES], wB[NWAVES], rSum[NWAVES], rSsq[NWAVES];

    const int t    = threadIdx.x;
    const int lane = t & 63;
    const int wv   = t >> 6;
    const long rbase = (long)blockIdx.x * T_COLS;

    // Uniform scalar parameter work -> SGPRs
    float ea_p = expf(p_alpha_log[0]);
    float eb_p = expf(p_beta_log[0]);
    float denom = 1.0f + ea_p + eb_p;
    float omega = rfl(expf(p_omega_log[0]));
    float alpha = rfl(ea_p / denom);
    float beta  = rfl(eb_p / denom);
    float b1 = beta, b2 = b1 * beta, b3 = b2 * beta, b4 = b3 * beta;

    // ---- Load: one float4 per thread; wave instr = 1KB contiguous (ideal) ----
    const float4* xv = reinterpret_cast<const float4*>(x + rbase);
    float4 v = xv[t];

    // prev = x[4t-1]: last element of thread t-1's float4
    float prev = __shfl_up(v.w, 1);
    if (lane == 0) prev = (t > 0) ? x[rbase + 4 * t - 1] : 0.0f;

    // ---- Per-thread sum/ssq ----
    float sum = (v.x + v.y) + (v.z + v.w);
    float ssq = fmaf(v.x, v.x, fmaf(v.y, v.y, fmaf(v.z, v.z, v.w * v.w)));

    // ---- Zero-init recurrence partials, saving intermediates ----
    // t>0 : 4 steps, inputs (prev, v.x, v.y, v.z): Z0..Z3, apart = beta^4
    // t==0: 3 steps, inputs (v.x, v.y, v.z):       Z1..Z3, apart = beta^3
    float Z0, Z1, Z2, Z3, apart;
    if (t > 0) {
        Z0 = fmaf(alpha, prev * prev, omega);
        Z1 = fmaf(beta, Z0, fmaf(alpha, v.x * v.x, omega));
        apart = b4;
    } else {
        Z0 = 0.0f;
        Z1 = fmaf(alpha, v.x * v.x, omega);
        apart = b3;
    }
    Z2 = fmaf(beta, Z1, fmaf(alpha, v.y * v.y, omega));
    Z3 = fmaf(beta, Z2, fmaf(alpha, v.z * v.z, omega));
    float bpart = Z3;

    // ---- Wave-level reduction (sum, ssq) ----
    float s1 = sum, s2 = ssq;
#pragma unroll
    for (int d = 32; d > 0; d >>= 1) {
        s1 += __shfl_xor(s1, d);
        s2 += __shfl_xor(s2, d);
    }

    // ---- Wave-level inclusive affine scan over (apart, bpart) ----
    float ia = apart, ib = bpart;
#pragma unroll
    for (int d = 1; d < 64; d <<= 1) {
        float pa = __shfl_up(ia, d);
        float pb = __shfl_up(ib, d);
        if (lane >= d) { ib = fmaf(ia, pb, ib); ia = ia * pa; }
    }

    // ---- Single cross-wave handoff barrier ----
    if (lane == 0)  { rSum[wv] = s1; rSsq[wv] = s2; }
    if (lane == 63) { wA[wv] = ia;   wB[wv] = ib;  }
    __syncthreads();

    // Block totals (16 broadcast LDS reads each — same-address, conflict-free)
    float tsum = 0.0f, tssq = 0.0f;
#pragma unroll
    for (int w = 0; w < NWAVES; ++w) { tsum += rSum[w]; tssq += rSsq[w]; }
    float s0 = (tssq - tsum * tsum * (1.0f / T_COLS)) * (1.0f / (T_COLS - 1));
    s0 = fmaxf(s0, 0.0f);

    // Apply preceding waves' aggregate maps to s0 (wave-uniform loop bound)
    float sw = s0;
    for (int w = 0; w < wv; ++w) sw = fmaf(wA[w], sw, wB[w]);

    // Exclusive intra-wave prefix -> entry state s = sigma2_{4t-1} (s0 for t==0)
    float pea = __shfl_up(ia, 1);
    float peb = __shfl_up(ib, 1);
    if (lane == 0) { pea = 1.0f; peb = 0.0f; }
    float s = fmaf(pea, sw, peb);

    // ---- Outputs: independent sqrt(beta^k * s + Z_k); one coalesced float4 store ----
    float4 o;
    if (t == 0) {
        o.x = __builtin_amdgcn_sqrtf(s);                  // sigma2_0 = s0
        o.y = __builtin_amdgcn_sqrtf(fmaf(b1, s, Z1));
        o.z = __builtin_amdgcn_sqrtf(fmaf(b2, s, Z2));
        o.w = __builtin_amdgcn_sqrtf(fmaf(b3, s, Z3));
    } else {
        o.x = __builtin_amdgcn_sqrtf(fmaf(b1, s, Z0));
        o.y = __builtin_amdgcn_sqrtf(fmaf(b2, s, Z1));
        o.z = __builtin_amdgcn_sqrtf(fmaf(b3, s, Z2));
        o.w = __builtin_amdgcn_sqrtf(fmaf(b4, s, Z3));
    }
    float4* ov = reinterpret_cast<float4*>(out + rbase);
    ov[t] = o;
}

extern "C" void kernel_launch(void* const* d_in, const int* in_sizes, int n_in,
                              void* d_out, int out_size, void* d_ws, size_t ws_size,
                              hipStream_t stream) {
    const float* x         = (const float*)d_in[0];
    const float* omega_log = (const float*)d_in[1];
    const float* alpha_log = (const float*)d_in[2];
    const float* beta_log  = (const float*)d_in[3];
    float* out = (float*)d_out;

    garch_fused<<<B_ROWS, NTHREADS, 0, stream>>>(x, omega_log, alpha_log, beta_log, out);
}

// Round 6
// 115.199 us; speedup vs baseline: 1.1222x; 1.1222x over previous
//
#include <hip/hip_runtime.h>
#include <math.h>

#define B_ROWS 4096
#define T_COLS 4096
#define NTHREADS 256
#define CHUNK 16                 // elements per thread
#define NWAVES (NTHREADS / 64)   // 4
#define CSTRIDE 20               // floats per chunk in LDS (16 data + 4 pad = 80B, b128-aligned)

// Force a (wave-uniform) float into an SGPR.
__device__ __forceinline__ float rfl(float v) {
    return __int_as_float(__builtin_amdgcn_readfirstlane(__float_as_int(v)));
}

__global__ __launch_bounds__(NTHREADS) void garch_fused(
    const float* __restrict__ x,
    const float* __restrict__ p_omega_log,
    const float* __restrict__ p_alpha_log,
    const float* __restrict__ p_beta_log,
    float* __restrict__ out)
{
    __shared__ float lds[NTHREADS * CSTRIDE];   // 20 KB
    __shared__ float wA[NWAVES], wB[NWAVES], rSum[NWAVES], rSsq[NWAVES];

    const int t    = threadIdx.x;
    const int lane = t & 63;
    const int wv   = t >> 6;
    const long rbase = (long)blockIdx.x * T_COLS;

    // Uniform scalar parameter work -> SGPRs
    float ea_p = expf(p_alpha_log[0]);
    float eb_p = expf(p_beta_log[0]);
    float denom = 1.0f + ea_p + eb_p;
    float omega = rfl(expf(p_omega_log[0]));
    float alpha = rfl(ea_p / denom);
    float beta  = rfl(eb_p / denom);

    float bpow[CHUNK + 1];
    bpow[0] = 1.0f;
#pragma unroll
    for (int j = 1; j <= CHUNK; ++j) bpow[j] = bpow[j - 1] * beta;

    // ---- Phase 0: coalesced global float4 loads -> padded LDS (b128 stores) ----
    const float4* xv = reinterpret_cast<const float4*>(x + rbase);
#pragma unroll
    for (int k = 0; k < 4; ++k) {
        int f = k * 256 + t;                   // float4 index within the row
        float4 v = xv[f];
        int c = f >> 2, j = f & 3;             // owning chunk, slot
        *reinterpret_cast<float4*>(&lds[c * CSTRIDE + j * 4]) = v;
    }
    __syncthreads();                           // barrier 1

    // ---- Phase 1: own chunk -> regs (4x ds_read_b128, bank-balanced) ----
    float xr[CHUNK];
#pragma unroll
    for (int j = 0; j < 4; ++j) {
        float4 v = *reinterpret_cast<const float4*>(&lds[t * CSTRIDE + j * 4]);
        xr[4 * j + 0] = v.x; xr[4 * j + 1] = v.y;
        xr[4 * j + 2] = v.z; xr[4 * j + 3] = v.w;
    }
    float prev = (t > 0) ? lds[(t - 1) * CSTRIDE + 15] : 0.0f;

    // ---- Per-thread sum/ssq ----
    float sum = 0.0f, ssq = 0.0f;
#pragma unroll
    for (int i = 0; i < CHUNK; ++i) { sum += xr[i]; ssq = fmaf(xr[i], xr[i], ssq); }

    // ---- Zero-init recurrence partials, saving intermediates Z[] ----
    // t>0 : steps with inputs (prev, xr[0..14]); Z[i] = chain value after step i.
    // t==0: steps with inputs xr[0..14]; Z[i+1] = chain value (Z[0] unused).
    float Z[CHUNK];
    float z;
    if (t > 0) { z = fmaf(alpha, prev * prev, omega); Z[0] = z; }
    else       { z = 0.0f;                            Z[0] = 0.0f; }
#pragma unroll
    for (int i = 0; i < CHUNK - 1; ++i) {
        z = fmaf(beta, z, fmaf(alpha, xr[i] * xr[i], omega));
        Z[i + 1] = z;
    }
    float bpart = z;
    float apart = (t == 0) ? bpow[15] : bpow[16];

    // ---- Wave-level reduction (sum, ssq) ----
    float s1 = sum, s2 = ssq;
#pragma unroll
    for (int d = 32; d > 0; d >>= 1) {
        s1 += __shfl_xor(s1, d);
        s2 += __shfl_xor(s2, d);
    }

    // ---- Wave-level inclusive affine scan over (apart, bpart) ----
    float ia = apart, ib = bpart;
#pragma unroll
    for (int d = 1; d < 64; d <<= 1) {
        float pa = __shfl_up(ia, d);
        float pb = __shfl_up(ib, d);
        if (lane >= d) { ib = fmaf(ia, pb, ib); ia = ia * pa; }
    }

    // ---- Cross-wave handoff (barrier 2; also fences all phase-1 LDS reads) ----
    if (lane == 0)  { rSum[wv] = s1; rSsq[wv] = s2; }
    if (lane == 63) { wA[wv] = ia;   wB[wv] = ib;  }
    __syncthreads();

    float tsum = rSum[0] + rSum[1] + rSum[2] + rSum[3];
    float tssq = rSsq[0] + rSsq[1] + rSsq[2] + rSsq[3];
    float s0 = (tssq - tsum * tsum * (1.0f / T_COLS)) * (1.0f / (T_COLS - 1));
    s0 = fmaxf(s0, 0.0f);

    // Apply preceding waves' aggregate maps to s0
    float sw = s0;
#pragma unroll
    for (int w = 0; w < NWAVES - 1; ++w)
        if (w < wv) sw = fmaf(wA[w], sw, wB[w]);

    // Exclusive intra-wave prefix -> entry state s = sigma2_{16t-1} (s0 for t==0)
    float pea = __shfl_up(ia, 1);
    float peb = __shfl_up(ib, 1);
    if (lane == 0) { pea = 1.0f; peb = 0.0f; }
    float s = fmaf(pea, sw, peb);

    // ---- Outputs: independent sqrt(beta^k*s + Z_k) -> own LDS chunk (b128) ----
    if (t == 0) {
        float4 q0;
        q0.x = __builtin_amdgcn_sqrtf(s);                         // sigma2_0 = s0
        q0.y = __builtin_amdgcn_sqrtf(fmaf(bpow[1], s, Z[1]));
        q0.z = __builtin_amdgcn_sqrtf(fmaf(bpow[2], s, Z[2]));
        q0.w = __builtin_amdgcn_sqrtf(fmaf(bpow[3], s, Z[3]));
        *reinterpret_cast<float4*>(&lds[t * CSTRIDE]) = q0;
#pragma unroll
        for (int k = 1; k < 4; ++k) {
            float4 q;
            q.x = __builtin_amdgcn_sqrtf(fmaf(bpow[4 * k + 0], s, Z[4 * k + 0]));
            q.y = __builtin_amdgcn_sqrtf(fmaf(bpow[4 * k + 1], s, Z[4 * k + 1]));
            q.z = __builtin_amdgcn_sqrtf(fmaf(bpow[4 * k + 2], s, Z[4 * k + 2]));
            q.w = __builtin_amdgcn_sqrtf(fmaf(bpow[4 * k + 3], s, Z[4 * k + 3]));
            *reinterpret_cast<float4*>(&lds[t * CSTRIDE + 4 * k]) = q;
        }
    } else {
#pragma unroll
        for (int k = 0; k < 4; ++k) {
            float4 q;
            q.x = __builtin_amdgcn_sqrtf(fmaf(bpow[4 * k + 1], s, Z[4 * k + 0]));
            q.y = __builtin_amdgcn_sqrtf(fmaf(bpow[4 * k + 2], s, Z[4 * k + 1]));
            q.z = __builtin_amdgcn_sqrtf(fmaf(bpow[4 * k + 3], s, Z[4 * k + 2]));
            q.w = __builtin_amdgcn_sqrtf(fmaf(bpow[4 * k + 4], s, Z[4 * k + 3]));
            *reinterpret_cast<float4*>(&lds[t * CSTRIDE + 4 * k]) = q;
        }
    }
    __syncthreads();                           // barrier 3

    // ---- Phase 4: padded LDS (b128 reads) -> coalesced global float4 stores ----
    float4* ov = reinterpret_cast<float4*>(out + rbase);
#pragma unroll
    for (int k = 0; k < 4; ++k) {
        int f = k * 256 + t;
        int c = f >> 2, j = f & 3;
        ov[f] = *reinterpret_cast<const float4*>(&lds[c * CSTRIDE + j * 4]);
    }
}

extern "C" void kernel_launch(void* const* d_in, const int* in_sizes, int n_in,
                              void* d_out, int out_size, void* d_ws, size_t ws_size,
                              hipStream_t stream) {
    const float* x         = (const float*)d_in[0];
    const float* omega_log = (const float*)d_in[1];
    const float* alpha_log = (const float*)d_in[2];
    const float* beta_log  = (const float*)d_in[3];
    float* out = (float*)d_out;

    garch_fused<<<B_ROWS, NTHREADS, 0, stream>>>(x, omega_log, alpha_log, beta_log, out);
}